// Round 13
// baseline (165.626 us; speedup 1.0000x reference)
//
#include <hip/hip_runtime.h>
#include <hip/hip_bf16.h>
#include <math.h>

// ---------------------------------------------------------------------------
// GCN 3-layer forward: gcn_norm (self-loops, sym D^-1/2) + 3x (GEMM -> CSR
// aggregate) with fused bias/ReLU and final log-softmax.
// R13: (1) tmp edges packed to uint32 ((col<<16)|row; N<2^16) -> halved
// bucketA LDS stage + tmp traffic. (2) bf16 inter-layer activations ->
// halved agg-write / gemm-read traffic. Agg mapping unchanged from R12.
// ---------------------------------------------------------------------------

#define BSHIFT 10           // bucket = col >> 10 (1024 nodes/bucket)
#define CHUNK 2048          // edges per bucketA workgroup
#define CAP 24576           // per-bucket edge capacity (mean 16384, +64 sigma)

__global__ __launch_bounds__(64) void tinyzero_kernel(int* __restrict__ p) {
  p[threadIdx.x] = 0;
}

// ---- phase 1: bucket edges by col>>BSHIFT into fixed-capacity regions ------
// packed edge: (col << 16) | row  (both < 2^16 for this problem size)

__global__ __launch_bounds__(256) void bucketA_kernel(const int* __restrict__ row,
                                                      const int* __restrict__ col,
                                                      int* __restrict__ bcursor,
                                                      unsigned int* __restrict__ tmp,
                                                      int e) {
  __shared__ int bcnt[64], bstart[64], bbase[64];
  __shared__ unsigned int stage[CHUNK];
  int tid = threadIdx.x;
  int base = blockIdx.x * CHUNK;
  int cnt = e - base;
  if (cnt > CHUNK) cnt = CHUNK;
  if (tid < 64) bcnt[tid] = 0;
  __syncthreads();

  unsigned int ed[CHUNK / 256];
  int rk[CHUNK / 256];
#pragma unroll
  for (int k = 0; k < CHUNK / 256; ++k) {
    int j = tid + k * 256;
    if (j < cnt) {
      int c = col[base + j], r = row[base + j];
      ed[k] = ((unsigned int)c << 16) | (unsigned int)r;
      rk[k] = atomicAdd(&bcnt[c >> BSHIFT], 1);
    }
  }
  __syncthreads();
  if (tid < 64) {  // wave 0: exclusive scan of bcnt + reserve bucket ranges
    int v = bcnt[tid];
    int run = v;
#pragma unroll
    for (int off = 1; off < 64; off <<= 1) {
      int t = __shfl_up(run, off);
      if (tid >= off) run += t;
    }
    bstart[tid] = run - v;
    if (v > 0) bbase[tid] = atomicAdd(&bcursor[tid], v);
  }
  __syncthreads();
#pragma unroll
  for (int k = 0; k < CHUNK / 256; ++k) {
    int j = tid + k * 256;
    if (j < cnt) stage[bstart[ed[k] >> (16 + BSHIFT)] + rk[k]] = ed[k];
  }
  __syncthreads();
  for (int s = tid; s < cnt; s += 256) {  // coalesced bucket-grouped write-out
    unsigned int ev = stage[s];
    int b = ev >> (16 + BSHIFT);
    tmp[(size_t)b * CAP + bbase[b] + (s - bstart[b])] = ev;
  }
}

// ---- phase 2: per-bucket LDS histogram + scan + scatter --------------------
// Emits meta[node] = {csr_offset, deg, dinv_bits, 0}, dinv[node], csr rows.

__global__ __launch_bounds__(256) void scatterB_kernel(const unsigned int* __restrict__ tmp,
                                                       const int* __restrict__ bcursor,
                                                       int4* __restrict__ meta,
                                                       float* __restrict__ dinv,
                                                       int* __restrict__ csr, int n) {
  __shared__ int cnt[1 << BSHIFT];
  __shared__ int part[256];
  int tid = threadIdx.x;
  int b = blockIdx.x;
  int node0 = b << BSHIFT;
  int m = bcursor[b];  // edges in this bucket
  const unsigned int* src = tmp + (size_t)b * CAP;

  for (int t = tid; t < (1 << BSHIFT); t += 256) cnt[t] = 0;
  __syncthreads();
  for (int i = tid; i < m; i += 256)
    atomicAdd(&cnt[(src[i] >> 16) & ((1 << BSHIFT) - 1)], 1);
  __syncthreads();

  int c0 = cnt[tid * 4 + 0], c1 = cnt[tid * 4 + 1];
  int c2 = cnt[tid * 4 + 2], c3 = cnt[tid * 4 + 3];
  int lsum = c0 + c1 + c2 + c3;
  part[tid] = lsum;
  __syncthreads();
#pragma unroll
  for (int off = 1; off < 256; off <<= 1) {
    int t = (tid >= off) ? part[tid - off] : 0;
    __syncthreads();
    part[tid] += t;
    __syncthreads();
  }
  int e0 = (tid == 0 ? 0 : part[tid - 1]);
  int e1 = e0 + c0, e2 = e1 + c1, e3 = e2 + c2;
  int base = b * CAP;  // csr is bucket-major with the same CAP

  int nd = node0 + tid * 4;
  if (nd + 0 < n) { float d = rsqrtf((float)(c0 + 1)); meta[nd + 0] = make_int4(base + e0, c0, __float_as_int(d), 0); dinv[nd + 0] = d; }
  if (nd + 1 < n) { float d = rsqrtf((float)(c1 + 1)); meta[nd + 1] = make_int4(base + e1, c1, __float_as_int(d), 0); dinv[nd + 1] = d; }
  if (nd + 2 < n) { float d = rsqrtf((float)(c2 + 1)); meta[nd + 2] = make_int4(base + e2, c2, __float_as_int(d), 0); dinv[nd + 2] = d; }
  if (nd + 3 < n) { float d = rsqrtf((float)(c3 + 1)); meta[nd + 3] = make_int4(base + e3, c3, __float_as_int(d), 0); dinv[nd + 3] = d; }
  __syncthreads();
  cnt[tid * 4 + 0] = e0; cnt[tid * 4 + 1] = e1;
  cnt[tid * 4 + 2] = e2; cnt[tid * 4 + 3] = e3;
  __syncthreads();

  for (int i = tid; i < m; i += 256) {
    unsigned int ev = src[i];
    int pos = atomicAdd(&cnt[(ev >> 16) & ((1 << BSHIFT) - 1)], 1);
    csr[base + pos] = (int)(ev & 0xFFFFu);
  }
}

// ---- bf16 helpers ----------------------------------------------------------

__device__ __forceinline__ float bflo(unsigned int u) {
  return __uint_as_float(u << 16);
}
__device__ __forceinline__ float bfhi(unsigned int u) {
  return __uint_as_float(u & 0xffff0000u);
}
__device__ __forceinline__ unsigned int pack2bf(float a, float b) {
  __hip_bfloat16 ha = __float2bfloat16(a), hb = __float2bfloat16(b);
  unsigned short ua = *(unsigned short*)&ha, ub = *(unsigned short*)&hb;
  return (unsigned int)ua | ((unsigned int)ub << 16);
}

// ---- dense GEMM: Hs[n][F] = bf16(dinv[n] * (X[n][K] @ W[K][F])) ------------
// BF16IN: X rows are bf16 (inter-layer activations); else f32 (input x).

template <int K, int F, bool BF16IN>
__global__ __launch_bounds__(256) void gemm_kernel(const void* __restrict__ Xv,
                                                   const float* __restrict__ W,
                                                   const float* __restrict__ dinv,
                                                   __hip_bfloat16* __restrict__ Y, int n) {
  __shared__ float xs[16][K];
  int tid = threadIdx.x;
  int node0 = blockIdx.x * 16;
  if (BF16IN) {
    constexpr int KV = K / 8;                 // uint4 = 8 bf16
    const uint4* X4 = (const uint4*)Xv;
    for (int i = tid; i < 16 * KV; i += 256) {
      int r = i / KV, c = i % KV;
      int nd = node0 + r;
      uint4 v = make_uint4(0u, 0u, 0u, 0u);
      if (nd < n) v = X4[(size_t)nd * KV + c];
      float4 lo = make_float4(bflo(v.x), bfhi(v.x), bflo(v.y), bfhi(v.y));
      float4 hi = make_float4(bflo(v.z), bfhi(v.z), bflo(v.w), bfhi(v.w));
      ((float4*)&xs[r][0])[c * 2] = lo;
      ((float4*)&xs[r][0])[c * 2 + 1] = hi;
    }
  } else {
    constexpr int KV = K / 4;
    const float4* X4 = (const float4*)Xv;
    for (int i = tid; i < 16 * KV; i += 256) {
      int r = i / KV, c = i % KV;
      int nd = node0 + r;
      float4 v = make_float4(0.f, 0.f, 0.f, 0.f);
      if (nd < n) v = X4[(size_t)nd * KV + c];
      ((float4*)&xs[r][0])[c] = v;
    }
  }
  __syncthreads();
  int g = tid >> 6, lane = tid & 63;
  if (lane < F) {
    float acc0 = 0.f, acc1 = 0.f, acc2 = 0.f, acc3 = 0.f;
#pragma unroll 8
    for (int k = 0; k < K; ++k) {
      float w = W[k * F + lane];
      acc0 += xs[g * 4 + 0][k] * w;
      acc1 += xs[g * 4 + 1][k] * w;
      acc2 += xs[g * 4 + 2][k] * w;
      acc3 += xs[g * 4 + 3][k] * w;
    }
    float accs[4] = {acc0, acc1, acc2, acc3};
#pragma unroll
    for (int j = 0; j < 4; ++j) {
      int nd = node0 + g * 4 + j;
      if (nd < n) Y[(size_t)nd * F + lane] = __float2bfloat16(accs[j] * dinv[nd]);
    }
  }
}

// ---- aggregate: quarter-wave per node, 8 lanes x uint4 per row -------------
// lane = q*16 + sub*8 + fid.  MODE 0: bias+ReLU -> bf16 activations.
// MODE 1: bias+log_softmax -> f32 out.

template <int F, int MODE>
__global__ __launch_bounds__(256) void agg_kernel(const unsigned short* __restrict__ Hs,
                                                  const int* __restrict__ csr,
                                                  const int4* __restrict__ meta,
                                                  const float* __restrict__ bias,
                                                  void* __restrict__ Yout, int n) {
  constexpr int FO = F / 8;                  // feature octets: 8 (F=64), 5 (F=40)
  int wv = (blockIdx.x * 256 + threadIdx.x) >> 6;
  int lane = threadIdx.x & 63;
  int q = lane >> 4;                         // node slot within wave
  int l16 = lane & 15;
  int sub = l16 >> 3;                        // edge slot within node
  int fid = lane & 7;                        // feature-octet id
  int node = wv * 4 + q;
  if (node >= n) return;
  bool activeF = (FO == 8) || (fid < FO);
  int qbase = q * 16;

  int4 mt = meta[node];                      // {off, deg, dinv_bits, 0}
  int s = mt.x, e = mt.x + mt.y;
  float di = __int_as_float(mt.z);

  float a0 = 0.f, a1 = 0.f, a2 = 0.f, a3 = 0.f;
  float a4 = 0.f, a5 = 0.f, a6 = 0.f, a7 = 0.f;
  if (sub == 0 && activeF) {                 // self-loop counted once
    uint4 u = *(const uint4*)(Hs + (size_t)node * F + 8 * fid);
    a0 = bflo(u.x); a1 = bfhi(u.x); a2 = bflo(u.y); a3 = bfhi(u.y);
    a4 = bflo(u.z); a5 = bfhi(u.z); a6 = bflo(u.w); a7 = bfhi(u.w);
  }

  for (int base = s; base < e; base += 16) {
    int rem = e - base;
    int cnt = rem < 16 ? rem : 16;
    int p = csr[base + (l16 < cnt ? l16 : 0)];   // 16 entries per node
    int j = 0;
    for (; j + 8 <= cnt; j += 8) {               // 8 edges/node per iter
      int r0 = __shfl(p, qbase + j + 0 + sub);
      int r1 = __shfl(p, qbase + j + 2 + sub);
      int r2 = __shfl(p, qbase + j + 4 + sub);
      int r3 = __shfl(p, qbase + j + 6 + sub);
      if (activeF) {
        uint4 u0 = *(const uint4*)(Hs + (size_t)r0 * F + 8 * fid);
        uint4 u1 = *(const uint4*)(Hs + (size_t)r1 * F + 8 * fid);
        uint4 u2 = *(const uint4*)(Hs + (size_t)r2 * F + 8 * fid);
        uint4 u3 = *(const uint4*)(Hs + (size_t)r3 * F + 8 * fid);
        a0 += bflo(u0.x); a1 += bfhi(u0.x); a2 += bflo(u0.y); a3 += bfhi(u0.y);
        a4 += bflo(u0.z); a5 += bfhi(u0.z); a6 += bflo(u0.w); a7 += bfhi(u0.w);
        a0 += bflo(u1.x); a1 += bfhi(u1.x); a2 += bflo(u1.y); a3 += bfhi(u1.y);
        a4 += bflo(u1.z); a5 += bfhi(u1.z); a6 += bflo(u1.w); a7 += bfhi(u1.w);
        a0 += bflo(u2.x); a1 += bfhi(u2.x); a2 += bflo(u2.y); a3 += bfhi(u2.y);
        a4 += bflo(u2.z); a5 += bfhi(u2.z); a6 += bflo(u2.w); a7 += bfhi(u2.w);
        a0 += bflo(u3.x); a1 += bfhi(u3.x); a2 += bflo(u3.y); a3 += bfhi(u3.y);
        a4 += bflo(u3.z); a5 += bfhi(u3.z); a6 += bflo(u3.w); a7 += bfhi(u3.w);
      }
    }
    for (; j < cnt; j += 2) {                    // tail (edge pairs via sub)
      int idx = j + sub;
      int r = __shfl(p, qbase + (idx < cnt ? idx : j));
      if (activeF && idx < cnt) {
        uint4 u = *(const uint4*)(Hs + (size_t)r * F + 8 * fid);
        a0 += bflo(u.x); a1 += bfhi(u.x); a2 += bflo(u.y); a3 += bfhi(u.y);
        a4 += bflo(u.z); a5 += bfhi(u.z); a6 += bflo(u.w); a7 += bfhi(u.w);
      }
    }
  }

  // combine the two edge slots (within node)
  a0 += __shfl_xor(a0, 8);
  a1 += __shfl_xor(a1, 8);
  a2 += __shfl_xor(a2, 8);
  a3 += __shfl_xor(a3, 8);
  a4 += __shfl_xor(a4, 8);
  a5 += __shfl_xor(a5, 8);
  a6 += __shfl_xor(a6, 8);
  a7 += __shfl_xor(a7, 8);

  if (MODE == 0) {
    if (sub == 0 && activeF) {
      float4 b0 = *(const float4*)(bias + 8 * fid);
      float4 b1 = *(const float4*)(bias + 8 * fid + 4);
      float v0 = a0 * di + b0.x, v1 = a1 * di + b0.y;
      float v2 = a2 * di + b0.z, v3 = a3 * di + b0.w;
      float v4 = a4 * di + b1.x, v5 = a5 * di + b1.y;
      float v6 = a6 * di + b1.z, v7 = a7 * di + b1.w;
      v0 = v0 > 0.f ? v0 : 0.f; v1 = v1 > 0.f ? v1 : 0.f;
      v2 = v2 > 0.f ? v2 : 0.f; v3 = v3 > 0.f ? v3 : 0.f;
      v4 = v4 > 0.f ? v4 : 0.f; v5 = v5 > 0.f ? v5 : 0.f;
      v6 = v6 > 0.f ? v6 : 0.f; v7 = v7 > 0.f ? v7 : 0.f;
      uint4 o;
      o.x = pack2bf(v0, v1); o.y = pack2bf(v2, v3);
      o.z = pack2bf(v4, v5); o.w = pack2bf(v6, v7);
      *(uint4*)((unsigned short*)Yout + (size_t)node * F + 8 * fid) = o;
    }
  } else {
    // log-softmax over F; reduction across the 8-lane fid group (xor 4,2,1)
    float v0 = -INFINITY, v1 = -INFINITY, v2 = -INFINITY, v3 = -INFINITY;
    float v4 = -INFINITY, v5 = -INFINITY, v6 = -INFINITY, v7 = -INFINITY;
    if (activeF) {
      float4 b0 = *(const float4*)(bias + 8 * fid);
      float4 b1 = *(const float4*)(bias + 8 * fid + 4);
      v0 = a0 * di + b0.x; v1 = a1 * di + b0.y;
      v2 = a2 * di + b0.z; v3 = a3 * di + b0.w;
      v4 = a4 * di + b1.x; v5 = a5 * di + b1.y;
      v6 = a6 * di + b1.z; v7 = a7 * di + b1.w;
    }
    float m = fmaxf(fmaxf(fmaxf(v0, v1), fmaxf(v2, v3)),
                    fmaxf(fmaxf(v4, v5), fmaxf(v6, v7)));
#pragma unroll
    for (int off = 4; off; off >>= 1) m = fmaxf(m, __shfl_xor(m, off));
    float ex = 0.f;
    if (activeF)
      ex = expf(v0 - m) + expf(v1 - m) + expf(v2 - m) + expf(v3 - m) +
           expf(v4 - m) + expf(v5 - m) + expf(v6 - m) + expf(v7 - m);
#pragma unroll
    for (int off = 4; off; off >>= 1) ex += __shfl_xor(ex, off);
    float lg = m + logf(ex);
    if (sub == 0 && activeF) {
      float* yp = (float*)Yout + (size_t)node * F + 8 * fid;
      *(float4*)yp = make_float4(v0 - lg, v1 - lg, v2 - lg, v3 - lg);
      *(float4*)(yp + 4) = make_float4(v4 - lg, v5 - lg, v6 - lg, v7 - lg);
    }
  }
}

// ---------------------------------------------------------------------------

extern "C" void kernel_launch(void* const* d_in, const int* in_sizes, int n_in,
                              void* d_out, int out_size, void* d_ws, size_t ws_size,
                              hipStream_t stream) {
  const float* x  = (const float*)d_in[0];
  const int*   ei = (const int*)d_in[1];
  const float* W1 = (const float*)d_in[2];
  const float* b1 = (const float*)d_in[3];
  const float* W2 = (const float*)d_in[4];
  const float* b2 = (const float*)d_in[5];
  const float* W3 = (const float*)d_in[6];
  const float* b3 = (const float*)d_in[7];
  float* out = (float*)d_out;

  const int N = in_sizes[0] / 128;
  const int E = in_sizes[1] / 2;
  const int* erow = ei;       // edge_index[0] = source
  const int* ecol = ei + E;   // edge_index[1] = target

  const int nbuckets = (N + (1 << BSHIFT) - 1) >> BSHIFT;  // 49 (<=64)

  auto align_up = [](size_t v) { return (v + 255) & ~(size_t)255; };
  char* ws = (char*)d_ws;
  size_t off = 0;
  int* bcursor  = (int*)(ws + off); off += align_up(64 * 4);
  int4* meta    = (int4*)(ws + off); off += align_up((size_t)N * 16);
  float* dinv   = (float*)(ws + off); off += align_up((size_t)N * 4);
  int* csr      = (int*)(ws + off); off += align_up((size_t)nbuckets * CAP * 4);
  unsigned int* tmp = (unsigned int*)(ws + off); off += align_up((size_t)nbuckets * CAP * 4);
  __hip_bfloat16* bufH = (__hip_bfloat16*)(ws + off); off += align_up((size_t)N * 64 * 2);
  __hip_bfloat16* bufA = (__hip_bfloat16*)(ws + off); off += align_up((size_t)N * 64 * 2);
  (void)ws_size;

  const int cb = (E + CHUNK - 1) / CHUNK;

  tinyzero_kernel<<<1, 64, 0, stream>>>(bcursor);
  bucketA_kernel<<<cb, 256, 0, stream>>>(erow, ecol, bcursor, tmp, E);
  scatterB_kernel<<<nbuckets, 256, 0, stream>>>(tmp, bcursor, meta, dinv, csr, N);

  const int gemm_blocks = (N + 15) / 16;
  const int agg_blocks = (N + 15) / 16;  // 4 waves x 4 nodes per 256-thread block

  gemm_kernel<128, 64, false><<<gemm_blocks, 256, 0, stream>>>(x, W1, dinv, bufH, N);
  agg_kernel<64, 0><<<agg_blocks, 256, 0, stream>>>((const unsigned short*)bufH, csr, meta, b1, bufA, N);

  gemm_kernel<64, 64, true><<<gemm_blocks, 256, 0, stream>>>(bufA, W2, dinv, bufH, N);
  agg_kernel<64, 0><<<agg_blocks, 256, 0, stream>>>((const unsigned short*)bufH, csr, meta, b2, bufA, N);

  gemm_kernel<64, 40, true><<<gemm_blocks, 256, 0, stream>>>(bufA, W3, dinv, bufH, N);
  agg_kernel<40, 1><<<agg_blocks, 256, 0, stream>>>((const unsigned short*)bufH, csr, meta, b3, out, N);
}